// Round 10
// baseline (406.670 us; speedup 1.0000x reference)
//
#include <hip/hip_runtime.h>
#include <math.h>

#define NN 100000
#define NE 1000000
#define CAP 32        // bucket capacity per node; degrees ~Poisson(10), max ~27
#define OVCAP 4096    // overflow list capacity (correct fallback, ~never used)
#define NWIN 489      // ceil(NE / 2048) edge windows
#define REGDIV 12500  // dst region r covers [r*12500, (r+1)*12500)
#define NDEG 391      // ceil(NN/256) degsum blocks
#define NGEMM 1024
#define NBKT 1024     // bucket-builder blocks
// H = 64 channels, hard-coded throughout.

// ---------------- bucket build, physically XCD-partitioned ----------------
// Each block reads its real XCD id (HW_REG_XCC_ID) and claims edge-windows
// for region==XCD via per-region tickets -> each 3.2MB bucket slice has a
// single writer XCD (L2 write-combining). After own region drains, blocks
// steal other regions' tickets (correct for ANY id values). R9 BUG FIXED:
// ticket claim is now BLOCK-uniform (thread 0 claims, LDS broadcast) — R9
// claimed per-thread, so each window was processed by a single thread and
// ~99% of edges were dropped.

__global__ __launch_bounds__(256) void k_bucket_xcd(const int* __restrict__ src,
                                                    const int* __restrict__ dst,
                                                    const float* __restrict__ ew,
                                                    int* __restrict__ cnt,
                                                    int2* __restrict__ bucket,
                                                    int4* __restrict__ ovf,
                                                    int* __restrict__ ovf_n,
                                                    int* __restrict__ ticket) {
  __shared__ int sw;
  int myreg;
  asm volatile("s_getreg_b32 %0, hwreg(HW_REG_XCC_ID, 0, 4)" : "=s"(myreg));
  myreg &= 7;
  for (int rr = 0; rr < 8; ++rr) {
    int r = (myreg + rr) & 7;
    int lo = r * REGDIV, hi = lo + REGDIV;
    while (true) {
      if (threadIdx.x == 0) {
        // steal-gate: for non-own regions, skip the claim if tickets are gone
        if (rr > 0 && *((volatile int*)&ticket[r]) >= NWIN) sw = NWIN;
        else sw = atomicAdd(&ticket[r], 1);
      }
      __syncthreads();
      int w = sw;
      __syncthreads();  // sw may be overwritten next iteration
      if (w >= NWIN) break;
      int base = w * 2048;
#pragma unroll
      for (int it = 0; it < 8; ++it) {
        int e = base + it * 256 + threadIdx.x;
        if (e < NE) {
          int d = dst[e];
          if (d >= lo && d < hi) {
            int s = src[e];
            float wv = ew[e];
            int pos = atomicAdd(&cnt[d], 1);
            if (pos < CAP) {
              bucket[d * CAP + pos] = make_int2(s, __float_as_int(wv));
            } else {
              int t = atomicAdd(ovf_n, 1);
              if (t < OVCAP) ovf[t] = make_int4(s, d, __float_as_int(wv), 0);
            }
          }
        }
      }
    }
  }
}

// ---------------- fused: degsum (needs bucket) + GEMM1 (independent) ----------------
// Block-split: [0,NDEG) = weighted degree from own bucket; [NDEG,..) = X@W1.

__global__ __launch_bounds__(256) void k_degsum_gemm(const int* __restrict__ cnt,
                                                     const int2* __restrict__ bucket,
                                                     const int4* __restrict__ ovf,
                                                     const int* __restrict__ ovf_n,
                                                     float* __restrict__ dinv,
                                                     const float* __restrict__ X,
                                                     const float* __restrict__ W,
                                                     float* __restrict__ Y) {
  int bid = blockIdx.x;
  if (bid < NDEG) {
    int i = bid * 256 + threadIdx.x;
    if (i >= NN) return;
    int c = cnt[i];
    int cc = c < CAP ? c : CAP;
    float dsum = 1.0f;  // self-loop weight
    const int2* bk = bucket + (size_t)i * CAP;
    for (int j = 0; j < cc; ++j) dsum += __int_as_float(bk[j].y);
    if (c > CAP) {
      int on = ovf_n[0]; if (on > OVCAP) on = OVCAP;
      for (int t = 0; t < on; ++t) {
        int4 o = ovf[t];
        if (o.y == i) dsum += __int_as_float(o.z);
      }
    }
    dinv[i] = 1.0f / sqrtf(dsum);
  } else {
    int lane = threadIdx.x & 63;
    int wid = (bid - NDEG) * 4 + (threadIdx.x >> 6);
    int nw = NGEMM * 4;
    float wcol[64];
#pragma unroll
    for (int k = 0; k < 64; ++k) wcol[k] = W[k * 64 + lane];
    for (int node = wid; node < NN; node += nw) {
      float xv = X[node * 64 + lane];
      float acc = 0.0f;
#pragma unroll
      for (int k = 0; k < 64; ++k) {
        float xb = __int_as_float(__builtin_amdgcn_readlane(__float_as_int(xv), k));
        acc = fmaf(xb, wcol[k], acc);
      }
      Y[node * 64 + lane] = acc;
    }
  }
}

// ---------------- 64x64 GEMM: Y[N,64] = X[N,64] @ W[64,64] ----------------

__global__ __launch_bounds__(256) void k_gemm64(const float* __restrict__ X,
                                                const float* __restrict__ W,
                                                float* __restrict__ Y) {
  int lane = threadIdx.x & 63;
  int wid = blockIdx.x * 4 + (threadIdx.x >> 6);
  int nw = gridDim.x * 4;
  float wcol[64];
#pragma unroll
  for (int k = 0; k < 64; ++k) wcol[k] = W[k * 64 + lane];
  for (int node = wid; node < NN; node += nw) {
    float xv = X[node * 64 + lane];
    float acc = 0.0f;
#pragma unroll
    for (int k = 0; k < 64; ++k) {
      float xb = __int_as_float(__builtin_amdgcn_readlane(__float_as_int(xv), k));
      acc = fmaf(xb, wcol[k], acc);
    }
    Y[node * 64 + lane] = acc;
  }
}

// ---------------- vectorized gather core ----------------
// Lane split: eg = lane>>4 (edge slot), cq = lane&15 (channel quad).
// Returns float4 acc valid in ALL lanes.

__device__ __forceinline__ float4 gather_row(const float* __restrict__ xw,
                                             const float* __restrict__ dinv,
                                             const int* __restrict__ cnt,
                                             const int2* __restrict__ bucket,
                                             const int4* __restrict__ ovf,
                                             const int* __restrict__ ovf_n,
                                             int node, int eg, int cq, float di) {
  int c = cnt[node];
  int cc = c < CAP ? c : CAP;
  const int2* bk = bucket + (size_t)node * CAP;
  float4 acc = make_float4(0.f, 0.f, 0.f, 0.f);

  int e0 = 0;
  for (; e0 + 8 <= cc; e0 += 8) {
    int2 Ea = bk[e0 + eg];
    int2 Eb = bk[e0 + 4 + eg];
    const float4 xa = *(const float4*)(xw + (size_t)Ea.x * 64 + cq * 4);
    const float4 xb = *(const float4*)(xw + (size_t)Eb.x * 64 + cq * 4);
    float va = dinv[Ea.x] * __int_as_float(Ea.y) * di;
    float vb = dinv[Eb.x] * __int_as_float(Eb.y) * di;
    acc.x = fmaf(xa.x, va, acc.x); acc.y = fmaf(xa.y, va, acc.y);
    acc.z = fmaf(xa.z, va, acc.z); acc.w = fmaf(xa.w, va, acc.w);
    acc.x = fmaf(xb.x, vb, acc.x); acc.y = fmaf(xb.y, vb, acc.y);
    acc.z = fmaf(xb.z, vb, acc.z); acc.w = fmaf(xb.w, vb, acc.w);
  }
  for (; e0 < cc; e0 += 4) {
    int e = e0 + eg;
    if (e < cc) {
      int2 E = bk[e];
      const float4 xa = *(const float4*)(xw + (size_t)E.x * 64 + cq * 4);
      float v = dinv[E.x] * __int_as_float(E.y) * di;
      acc.x = fmaf(xa.x, v, acc.x); acc.y = fmaf(xa.y, v, acc.y);
      acc.z = fmaf(xa.z, v, acc.z); acc.w = fmaf(xa.w, v, acc.w);
    }
  }
  acc.x += __shfl_xor(acc.x, 16, 64); acc.y += __shfl_xor(acc.y, 16, 64);
  acc.z += __shfl_xor(acc.z, 16, 64); acc.w += __shfl_xor(acc.w, 16, 64);
  acc.x += __shfl_xor(acc.x, 32, 64); acc.y += __shfl_xor(acc.y, 32, 64);
  acc.z += __shfl_xor(acc.z, 32, 64); acc.w += __shfl_xor(acc.w, 32, 64);

  if (c > CAP) {
    int on = ovf_n[0]; if (on > OVCAP) on = OVCAP;
    for (int t = 0; t < on; ++t) {
      int4 o = ovf[t];
      if (o.y == node) {
        const float4 xa = *(const float4*)(xw + (size_t)o.x * 64 + cq * 4);
        float v = dinv[o.x] * __int_as_float(o.z) * di;
        acc.x = fmaf(xa.x, v, acc.x); acc.y = fmaf(xa.y, v, acc.y);
        acc.z = fmaf(xa.z, v, acc.z); acc.w = fmaf(xa.w, v, acc.w);
      }
    }
  }
  const float4 xs = *(const float4*)(xw + (size_t)node * 64 + cq * 4);
  float dd = di * di;
  acc.x = fmaf(xs.x, dd, acc.x); acc.y = fmaf(xs.y, dd, acc.y);
  acc.z = fmaf(xs.z, dd, acc.z); acc.w = fmaf(xs.w, dd, acc.w);
  return acc;
}

// ---------------- layer-1 aggregation: gather + bias + ReLU ----------------

__global__ __launch_bounds__(256) void k_gather_l1(const float* __restrict__ xw,
                                                   const float* __restrict__ dinv,
                                                   const int* __restrict__ cnt,
                                                   const int2* __restrict__ bucket,
                                                   const int4* __restrict__ ovf,
                                                   const int* __restrict__ ovf_n,
                                                   const float* __restrict__ b,
                                                   float* __restrict__ h) {
  int lane = threadIdx.x & 63;
  int node = blockIdx.x * 4 + (threadIdx.x >> 6);
  if (node >= NN) return;
  int eg = lane >> 4, cq = lane & 15;
  float di = dinv[node];
  float4 acc = gather_row(xw, dinv, cnt, bucket, ovf, ovf_n, node, eg, cq, di);
  const float4 b4 = *(const float4*)(b + cq * 4);
  float4 r;
  r.x = fmaxf(acc.x + b4.x, 0.f); r.y = fmaxf(acc.y + b4.y, 0.f);
  r.z = fmaxf(acc.z + b4.z, 0.f); r.w = fmaxf(acc.w + b4.w, 0.f);
  if (lane < 16) *(float4*)(h + (size_t)node * 64 + cq * 4) = r;
}

// ---------------- layer-2 aggregation fused with both heads ----------------

__global__ __launch_bounds__(256) void k_gather_l2_heads(const float* __restrict__ xw,
                                                         const float* __restrict__ dinv,
                                                         const int* __restrict__ cnt,
                                                         const int2* __restrict__ bucket,
                                                         const int4* __restrict__ ovf,
                                                         const int* __restrict__ ovf_n,
                                                         const float* __restrict__ b2,
                                                         const float* __restrict__ Wn,
                                                         const float* __restrict__ bn,
                                                         const float* __restrict__ Wr,
                                                         const float* __restrict__ br,
                                                         float* __restrict__ logits,
                                                         float* __restrict__ rr) {
  int lane = threadIdx.x & 63;
  int node = blockIdx.x * 4 + (threadIdx.x >> 6);
  if (node >= NN) return;
  int eg = lane >> 4, cq = lane & 15;
  float di = dinv[node];
  float4 acc = gather_row(xw, dinv, cnt, bucket, ovf, ovf_n, node, eg, cq, di);
  const float4 b4 = *(const float4*)(b2 + cq * 4);
  float4 r;
  r.x = fmaxf(acc.x + b4.x, 0.f); r.y = fmaxf(acc.y + b4.y, 0.f);
  r.z = fmaxf(acc.z + b4.z, 0.f); r.w = fmaxf(acc.w + b4.w, 0.f);
  const float4 wn4 = *(const float4*)(Wn + cq * 4);
  const float4 wr4 = *(const float4*)(Wr + cq * 4);
  float an = r.x * wn4.x + r.y * wn4.y + r.z * wn4.z + r.w * wn4.w;
  float ar = r.x * wr4.x + r.y * wr4.y + r.z * wr4.z + r.w * wr4.w;
#pragma unroll
  for (int m = 8; m > 0; m >>= 1) {
    an += __shfl_xor(an, m, 64);
    ar += __shfl_xor(ar, m, 64);
  }
  if (lane == 0) {
    logits[node] = an + bn[0];
    float xr = ar + br[0];
    rr[node] = 0.01f / (1.0f + expf(-xr));
  }
}

// ---------------- softmax ----------------

#define RB 256  // reduction grid

__global__ __launch_bounds__(256) void k_smax_partial(const float* __restrict__ logits,
                                                      float* __restrict__ part) {
  __shared__ float s[256];
  float m = -INFINITY;
  for (int i = blockIdx.x * 256 + threadIdx.x; i < NN; i += RB * 256)
    m = fmaxf(m, logits[i]);
  s[threadIdx.x] = m;
  __syncthreads();
  for (int w = 128; w > 0; w >>= 1) {
    if (threadIdx.x < w) s[threadIdx.x] = fmaxf(s[threadIdx.x], s[threadIdx.x + w]);
    __syncthreads();
  }
  if (threadIdx.x == 0) part[blockIdx.x] = s[0];
}

__global__ __launch_bounds__(256) void k_smax_final(const float* __restrict__ part,
                                                    float* __restrict__ gmax) {
  __shared__ float s[256];
  s[threadIdx.x] = part[threadIdx.x];
  __syncthreads();
  for (int w = 128; w > 0; w >>= 1) {
    if (threadIdx.x < w) s[threadIdx.x] = fmaxf(s[threadIdx.x], s[threadIdx.x + w]);
    __syncthreads();
  }
  if (threadIdx.x == 0) gmax[0] = s[0];
}

// exp + block sums + 256-atomic global sum (256 funnel atomics ~ 4us, OK)
__global__ __launch_bounds__(256) void k_sexp(const float* __restrict__ logits,
                                              const float* __restrict__ gmax,
                                              float* __restrict__ sel,
                                              float* __restrict__ gsum) {
  __shared__ float s[256];
  float m = gmax[0];
  float acc = 0.0f;
  for (int i = blockIdx.x * 256 + threadIdx.x; i < NN; i += RB * 256) {
    float e = expf(logits[i] - m);
    sel[i] = e;
    acc += e;
  }
  s[threadIdx.x] = acc;
  __syncthreads();
  for (int w = 128; w > 0; w >>= 1) {
    if (threadIdx.x < w) s[threadIdx.x] += s[threadIdx.x + w];
    __syncthreads();
  }
  if (threadIdx.x == 0) unsafeAtomicAdd(gsum, s[0]);
}

__global__ __launch_bounds__(256) void k_snorm(float* __restrict__ sel,
                                               const float* __restrict__ gsum) {
  int i = blockIdx.x * 256 + threadIdx.x;
  if (i < NN) sel[i] *= (1.0f / gsum[0]);
}

// ---------------- launch ----------------

extern "C" void kernel_launch(void* const* d_in, const int* in_sizes, int n_in,
                              void* d_out, int out_size, void* d_ws, size_t ws_size,
                              hipStream_t stream) {
  const float* x  = (const float*)d_in[0];
  const int*   ei = (const int*)d_in[1];   // [2, E]: src row then dst row
  const float* ew = (const float*)d_in[2];
  const float* W1 = (const float*)d_in[3];
  const float* b1 = (const float*)d_in[4];
  const float* W2 = (const float*)d_in[5];
  const float* b2 = (const float*)d_in[6];
  const float* Wn = (const float*)d_in[7];
  const float* bn = (const float*)d_in[8];
  const float* Wr = (const float*)d_in[9];
  const float* br = (const float*)d_in[10];
  const int* src = ei;
  const int* dst = ei + NE;

  // ws layout — float4/int2/int4 regions start at word offsets %4==0.
  float* ws = (float*)d_ws;
  float* xw      = ws;                                 // 6,400,000 words
  float* h       = xw + (size_t)NN * 64;               // 6,400,000
  float* dinv    = h + (size_t)NN * 64;                // 100,000
  float* logits  = dinv + NN;                          // 100,000
  int2*  bucket  = (int2*)(logits + NN);               // word 13,000,000 (%4==0)
  int4*  ovf     = (int4*)(bucket + (size_t)NN * CAP); // word 19,400,000 (%4==0)
  int*   cnt     = (int*)(ovf + OVCAP);                // NN   -- memset from here
  int*   ovf_n   = cnt + NN;                           // 1
  int*   ticket  = ovf_n + 1;                          // 8
  float* gsum    = (float*)(ticket + 8);               // 1   -- memset to here
  float* part1   = gsum + 1;                           // 256
  float* gmax    = part1 + 256;                        // 1

  float* sel = (float*)d_out;                          // node_selector [N]
  float* rr  = (float*)d_out + NN;                     // rescue_ratios [N]

  int gN  = (NN + 255) / 256;
  int gN4 = NN / 4;  // NN % 4 == 0

  // zero cnt + ovf_n + ticket + gsum in one memset
  hipMemsetAsync(cnt, 0, (size_t)(NN + 10) * 4, stream);

  // ---- bucket build, physically XCD-partitioned ----
  k_bucket_xcd<<<NBKT, 256, 0, stream>>>(src, dst, ew, cnt, bucket, ovf, ovf_n,
                                         ticket);

  // ---- degsum (bucket-dependent) co-scheduled with GEMM1 (independent) ----
  k_degsum_gemm<<<NDEG + NGEMM, 256, 0, stream>>>(cnt, bucket, ovf, ovf_n, dinv,
                                                  x, W1, xw);

  // ---- layer 1 aggregation ----
  k_gather_l1<<<gN4, 256, 0, stream>>>(xw, dinv, cnt, bucket, ovf, ovf_n, b1, h);

  // ---- layer 2: gemm -> gather fused with heads ----
  k_gemm64<<<1024, 256, 0, stream>>>(h, W2, xw);
  k_gather_l2_heads<<<gN4, 256, 0, stream>>>(xw, dinv, cnt, bucket, ovf, ovf_n,
                                             b2, Wn, bn, Wr, br, logits, rr);

  // ---- softmax ----
  k_smax_partial<<<RB, 256, 0, stream>>>(logits, part1);
  k_smax_final<<<1, 256, 0, stream>>>(part1, gmax);
  k_sexp<<<RB, 256, 0, stream>>>(logits, gmax, sel, gsum);
  k_snorm<<<gN, 256, 0, stream>>>(sel, gsum);
}

// Round 11
// 320.099 us; speedup vs baseline: 1.2705x; 1.2705x over previous
//
#include <hip/hip_runtime.h>
#include <math.h>

#define NN 100000
#define NE 1000000
#define CAP 32        // bucket capacity per node; degrees ~Poisson(10), max ~27
#define OVCAP 4096    // overflow list capacity (correct fallback, ~never used)
#define NDEG 391      // ceil(NN/256) degsum blocks
#define NGEMM 1024
#define NEB 3907      // ceil(NE/256) bucket blocks
// H = 64 channels, hard-coded throughout.

// ---------------- bucket build (R6 form: 1 edge/thread, 1 atomic + 1 store) ----------------
// R10 falsified the XCD-partitioning theory: bucket writeback (~60MB) is
// temporal (same-line writes are ~100k edges apart -> line evicted between
// touches, ~1 writeback/edge) and is invariant to writer placement. This
// simple single-pass form is the measured floor (~75us, R6).

__global__ __launch_bounds__(256) void k_bucket(const int* __restrict__ src,
                                                const int* __restrict__ dst,
                                                const float* __restrict__ ew,
                                                int* __restrict__ cnt,
                                                int2* __restrict__ bucket,
                                                int4* __restrict__ ovf,
                                                int* __restrict__ ovf_n) {
  int e = blockIdx.x * 256 + threadIdx.x;
  if (e < NE) {
    int s = src[e];
    int d = dst[e];
    float w = ew[e];
    int pos = atomicAdd(&cnt[d], 1);
    if (pos < CAP) {
      bucket[d * CAP + pos] = make_int2(s, __float_as_int(w));
    } else {
      int t = atomicAdd(ovf_n, 1);
      if (t < OVCAP) ovf[t] = make_int4(s, d, __float_as_int(w), 0);
    }
  }
}

// ---------------- fused: degsum (needs bucket) + GEMM1 (independent) ----------------

__global__ __launch_bounds__(256) void k_degsum_gemm(const int* __restrict__ cnt,
                                                     const int2* __restrict__ bucket,
                                                     const int4* __restrict__ ovf,
                                                     const int* __restrict__ ovf_n,
                                                     float* __restrict__ dinv,
                                                     const float* __restrict__ X,
                                                     const float* __restrict__ W,
                                                     float* __restrict__ Y) {
  int bid = blockIdx.x;
  if (bid < NDEG) {
    int i = bid * 256 + threadIdx.x;
    if (i >= NN) return;
    int c = cnt[i];
    int cc = c < CAP ? c : CAP;
    float dsum = 1.0f;  // self-loop weight
    const int2* bk = bucket + (size_t)i * CAP;
    for (int j = 0; j < cc; ++j) dsum += __int_as_float(bk[j].y);
    if (c > CAP) {
      int on = ovf_n[0]; if (on > OVCAP) on = OVCAP;
      for (int t = 0; t < on; ++t) {
        int4 o = ovf[t];
        if (o.y == i) dsum += __int_as_float(o.z);
      }
    }
    dinv[i] = 1.0f / sqrtf(dsum);
  } else {
    int lane = threadIdx.x & 63;
    int wid = (bid - NDEG) * 4 + (threadIdx.x >> 6);
    int nw = NGEMM * 4;
    float wcol[64];
#pragma unroll
    for (int k = 0; k < 64; ++k) wcol[k] = W[k * 64 + lane];
    for (int node = wid; node < NN; node += nw) {
      float xv = X[node * 64 + lane];
      float acc = 0.0f;
#pragma unroll
      for (int k = 0; k < 64; ++k) {
        float xb = __int_as_float(__builtin_amdgcn_readlane(__float_as_int(xv), k));
        acc = fmaf(xb, wcol[k], acc);
      }
      Y[node * 64 + lane] = acc;
    }
  }
}

// ---------------- 64x64 GEMM: Y[N,64] = X[N,64] @ W[64,64] ----------------

__global__ __launch_bounds__(256) void k_gemm64(const float* __restrict__ X,
                                                const float* __restrict__ W,
                                                float* __restrict__ Y) {
  int lane = threadIdx.x & 63;
  int wid = blockIdx.x * 4 + (threadIdx.x >> 6);
  int nw = gridDim.x * 4;
  float wcol[64];
#pragma unroll
  for (int k = 0; k < 64; ++k) wcol[k] = W[k * 64 + lane];
  for (int node = wid; node < NN; node += nw) {
    float xv = X[node * 64 + lane];
    float acc = 0.0f;
#pragma unroll
    for (int k = 0; k < 64; ++k) {
      float xb = __int_as_float(__builtin_amdgcn_readlane(__float_as_int(xv), k));
      acc = fmaf(xb, wcol[k], acc);
    }
    Y[node * 64 + lane] = acc;
  }
}

// ---------------- gather core: 4 nodes per wave, 16 lanes per node ----------------
// l = lane&15 owns channel quad l (float4 of the row); node is uniform across
// its 16-lane group. 4-deep edge unroll -> 4 independent 1KB wave-loads in
// flight x 4 node-groups = 8x the MLP of the old 1-node/wave form. No
// cross-edge shfl. Bucket slots read as int4 pairs (2 loads per 4 edges).

__device__ __forceinline__ float4 gather_node(const float* __restrict__ xw,
                                              const float* __restrict__ dinv,
                                              const int* __restrict__ cnt,
                                              const int2* __restrict__ bucket,
                                              const int4* __restrict__ ovf,
                                              const int* __restrict__ ovf_n,
                                              int node, int l, float di) {
  int c = cnt[node];
  int cc = c < CAP ? c : CAP;
  const int4* bk4 = (const int4*)(bucket + (size_t)node * CAP);
  float4 acc = make_float4(0.f, 0.f, 0.f, 0.f);

  int j = 0;
  for (; j + 4 <= cc; j += 4) {
    int4 pa = bk4[j >> 1];
    int4 pb = bk4[(j >> 1) + 1];
    const float4 x0 = *(const float4*)(xw + (size_t)pa.x * 64 + l * 4);
    const float4 x1 = *(const float4*)(xw + (size_t)pa.z * 64 + l * 4);
    const float4 x2 = *(const float4*)(xw + (size_t)pb.x * 64 + l * 4);
    const float4 x3 = *(const float4*)(xw + (size_t)pb.z * 64 + l * 4);
    float v0 = dinv[pa.x] * __int_as_float(pa.y) * di;
    float v1 = dinv[pa.z] * __int_as_float(pa.w) * di;
    float v2 = dinv[pb.x] * __int_as_float(pb.y) * di;
    float v3 = dinv[pb.z] * __int_as_float(pb.w) * di;
    acc.x = fmaf(x0.x, v0, acc.x); acc.y = fmaf(x0.y, v0, acc.y);
    acc.z = fmaf(x0.z, v0, acc.z); acc.w = fmaf(x0.w, v0, acc.w);
    acc.x = fmaf(x1.x, v1, acc.x); acc.y = fmaf(x1.y, v1, acc.y);
    acc.z = fmaf(x1.z, v1, acc.z); acc.w = fmaf(x1.w, v1, acc.w);
    acc.x = fmaf(x2.x, v2, acc.x); acc.y = fmaf(x2.y, v2, acc.y);
    acc.z = fmaf(x2.z, v2, acc.z); acc.w = fmaf(x2.w, v2, acc.w);
    acc.x = fmaf(x3.x, v3, acc.x); acc.y = fmaf(x3.y, v3, acc.y);
    acc.z = fmaf(x3.z, v3, acc.z); acc.w = fmaf(x3.w, v3, acc.w);
  }
  const int2* bk = (const int2*)bk4;
  for (; j < cc; ++j) {
    int2 E = bk[j];
    const float4 xa = *(const float4*)(xw + (size_t)E.x * 64 + l * 4);
    float v = dinv[E.x] * __int_as_float(E.y) * di;
    acc.x = fmaf(xa.x, v, acc.x); acc.y = fmaf(xa.y, v, acc.y);
    acc.z = fmaf(xa.z, v, acc.z); acc.w = fmaf(xa.w, v, acc.w);
  }
  if (c > CAP) {
    int on = ovf_n[0]; if (on > OVCAP) on = OVCAP;
    for (int t = 0; t < on; ++t) {
      int4 o = ovf[t];
      if (o.y == node) {
        const float4 xa = *(const float4*)(xw + (size_t)o.x * 64 + l * 4);
        float v = dinv[o.x] * __int_as_float(o.z) * di;
        acc.x = fmaf(xa.x, v, acc.x); acc.y = fmaf(xa.y, v, acc.y);
        acc.z = fmaf(xa.z, v, acc.z); acc.w = fmaf(xa.w, v, acc.w);
      }
    }
  }
  // self-loop
  const float4 xs = *(const float4*)(xw + (size_t)node * 64 + l * 4);
  float dd = di * di;
  acc.x = fmaf(xs.x, dd, acc.x); acc.y = fmaf(xs.y, dd, acc.y);
  acc.z = fmaf(xs.z, dd, acc.z); acc.w = fmaf(xs.w, dd, acc.w);
  return acc;
}

// ---------------- layer-1 aggregation: gather + bias + ReLU ----------------
// 16 nodes per block (4 waves x 4 node-groups). NN = 6250*16 exactly.

__global__ __launch_bounds__(256) void k_gather_l1(const float* __restrict__ xw,
                                                   const float* __restrict__ dinv,
                                                   const int* __restrict__ cnt,
                                                   const int2* __restrict__ bucket,
                                                   const int4* __restrict__ ovf,
                                                   const int* __restrict__ ovf_n,
                                                   const float* __restrict__ b,
                                                   float* __restrict__ h) {
  int l = threadIdx.x & 15;
  int node = blockIdx.x * 16 + (threadIdx.x >> 4);
  float di = dinv[node];
  float4 acc = gather_node(xw, dinv, cnt, bucket, ovf, ovf_n, node, l, di);
  const float4 b4 = *(const float4*)(b + l * 4);
  float4 r;
  r.x = fmaxf(acc.x + b4.x, 0.f); r.y = fmaxf(acc.y + b4.y, 0.f);
  r.z = fmaxf(acc.z + b4.z, 0.f); r.w = fmaxf(acc.w + b4.w, 0.f);
  *(float4*)(h + (size_t)node * 64 + l * 4) = r;  // full-wave 1KB store
}

// ---------------- layer-2 aggregation fused with both heads ----------------

__global__ __launch_bounds__(256) void k_gather_l2_heads(const float* __restrict__ xw,
                                                         const float* __restrict__ dinv,
                                                         const int* __restrict__ cnt,
                                                         const int2* __restrict__ bucket,
                                                         const int4* __restrict__ ovf,
                                                         const int* __restrict__ ovf_n,
                                                         const float* __restrict__ b2,
                                                         const float* __restrict__ Wn,
                                                         const float* __restrict__ bn,
                                                         const float* __restrict__ Wr,
                                                         const float* __restrict__ br,
                                                         float* __restrict__ logits,
                                                         float* __restrict__ rr) {
  int l = threadIdx.x & 15;
  int node = blockIdx.x * 16 + (threadIdx.x >> 4);
  float di = dinv[node];
  float4 acc = gather_node(xw, dinv, cnt, bucket, ovf, ovf_n, node, l, di);
  const float4 b4 = *(const float4*)(b2 + l * 4);
  float4 r;
  r.x = fmaxf(acc.x + b4.x, 0.f); r.y = fmaxf(acc.y + b4.y, 0.f);
  r.z = fmaxf(acc.z + b4.z, 0.f); r.w = fmaxf(acc.w + b4.w, 0.f);
  const float4 wn4 = *(const float4*)(Wn + l * 4);
  const float4 wr4 = *(const float4*)(Wr + l * 4);
  float an = r.x * wn4.x + r.y * wn4.y + r.z * wn4.z + r.w * wn4.w;
  float ar = r.x * wr4.x + r.y * wr4.y + r.z * wr4.z + r.w * wr4.w;
  // reduce within the 16-lane node-group (masks stay inside the group)
#pragma unroll
  for (int m = 8; m > 0; m >>= 1) {
    an += __shfl_xor(an, m, 64);
    ar += __shfl_xor(ar, m, 64);
  }
  if (l == 0) {
    logits[node] = an + bn[0];
    float xr = ar + br[0];
    rr[node] = 0.01f / (1.0f + expf(-xr));
  }
}

// ---------------- softmax ----------------

#define RB 256  // reduction grid

__global__ __launch_bounds__(256) void k_smax_partial(const float* __restrict__ logits,
                                                      float* __restrict__ part) {
  __shared__ float s[256];
  float m = -INFINITY;
  for (int i = blockIdx.x * 256 + threadIdx.x; i < NN; i += RB * 256)
    m = fmaxf(m, logits[i]);
  s[threadIdx.x] = m;
  __syncthreads();
  for (int w = 128; w > 0; w >>= 1) {
    if (threadIdx.x < w) s[threadIdx.x] = fmaxf(s[threadIdx.x], s[threadIdx.x + w]);
    __syncthreads();
  }
  if (threadIdx.x == 0) part[blockIdx.x] = s[0];
}

__global__ __launch_bounds__(256) void k_smax_final(const float* __restrict__ part,
                                                    float* __restrict__ gmax) {
  __shared__ float s[256];
  s[threadIdx.x] = part[threadIdx.x];
  __syncthreads();
  for (int w = 128; w > 0; w >>= 1) {
    if (threadIdx.x < w) s[threadIdx.x] = fmaxf(s[threadIdx.x], s[threadIdx.x + w]);
    __syncthreads();
  }
  if (threadIdx.x == 0) gmax[0] = s[0];
}

// exp + block sums + 256-atomic global sum (256 funnel atomics ~ 4us, OK)
__global__ __launch_bounds__(256) void k_sexp(const float* __restrict__ logits,
                                              const float* __restrict__ gmax,
                                              float* __restrict__ sel,
                                              float* __restrict__ gsum) {
  __shared__ float s[256];
  float m = gmax[0];
  float acc = 0.0f;
  for (int i = blockIdx.x * 256 + threadIdx.x; i < NN; i += RB * 256) {
    float e = expf(logits[i] - m);
    sel[i] = e;
    acc += e;
  }
  s[threadIdx.x] = acc;
  __syncthreads();
  for (int w = 128; w > 0; w >>= 1) {
    if (threadIdx.x < w) s[threadIdx.x] += s[threadIdx.x + w];
    __syncthreads();
  }
  if (threadIdx.x == 0) unsafeAtomicAdd(gsum, s[0]);
}

__global__ __launch_bounds__(256) void k_snorm(float* __restrict__ sel,
                                               const float* __restrict__ gsum) {
  int i = blockIdx.x * 256 + threadIdx.x;
  if (i < NN) sel[i] *= (1.0f / gsum[0]);
}

// ---------------- launch ----------------

extern "C" void kernel_launch(void* const* d_in, const int* in_sizes, int n_in,
                              void* d_out, int out_size, void* d_ws, size_t ws_size,
                              hipStream_t stream) {
  const float* x  = (const float*)d_in[0];
  const int*   ei = (const int*)d_in[1];   // [2, E]: src row then dst row
  const float* ew = (const float*)d_in[2];
  const float* W1 = (const float*)d_in[3];
  const float* b1 = (const float*)d_in[4];
  const float* W2 = (const float*)d_in[5];
  const float* b2 = (const float*)d_in[6];
  const float* Wn = (const float*)d_in[7];
  const float* bn = (const float*)d_in[8];
  const float* Wr = (const float*)d_in[9];
  const float* br = (const float*)d_in[10];
  const int* src = ei;
  const int* dst = ei + NE;

  // ws layout — float4/int2/int4 regions start at word offsets %4==0.
  float* ws = (float*)d_ws;
  float* xw      = ws;                                 // 6,400,000 words
  float* h       = xw + (size_t)NN * 64;               // 6,400,000
  float* dinv    = h + (size_t)NN * 64;                // 100,000
  float* logits  = dinv + NN;                          // 100,000
  int2*  bucket  = (int2*)(logits + NN);               // word 13,000,000 (%4==0)
  int4*  ovf     = (int4*)(bucket + (size_t)NN * CAP); // word 19,400,000 (%4==0)
  int*   cnt     = (int*)(ovf + OVCAP);                // NN   -- memset from here
  int*   ovf_n   = cnt + NN;                           // 1
  float* gsum    = (float*)(ovf_n + 1);                // 1   -- memset to here
  float* part1   = gsum + 1;                           // 256
  float* gmax    = part1 + 256;                        // 1

  float* sel = (float*)d_out;                          // node_selector [N]
  float* rr  = (float*)d_out + NN;                     // rescue_ratios [N]

  int gN   = (NN + 255) / 256;
  int gN16 = NN / 16;  // 6250, exact

  // zero cnt + ovf_n + gsum in one memset
  hipMemsetAsync(cnt, 0, (size_t)(NN + 2) * 4, stream);

  // ---- bucket build (single-pass, R6 form) ----
  k_bucket<<<NEB, 256, 0, stream>>>(src, dst, ew, cnt, bucket, ovf, ovf_n);

  // ---- degsum (bucket-dependent) co-scheduled with GEMM1 (independent) ----
  k_degsum_gemm<<<NDEG + NGEMM, 256, 0, stream>>>(cnt, bucket, ovf, ovf_n, dinv,
                                                  x, W1, xw);

  // ---- layer 1 aggregation ----
  k_gather_l1<<<gN16, 256, 0, stream>>>(xw, dinv, cnt, bucket, ovf, ovf_n, b1, h);

  // ---- layer 2: gemm -> gather fused with heads ----
  k_gemm64<<<1024, 256, 0, stream>>>(h, W2, xw);
  k_gather_l2_heads<<<gN16, 256, 0, stream>>>(xw, dinv, cnt, bucket, ovf, ovf_n,
                                              b2, Wn, bn, Wr, br, logits, rr);

  // ---- softmax ----
  k_smax_partial<<<RB, 256, 0, stream>>>(logits, part1);
  k_smax_final<<<1, 256, 0, stream>>>(part1, gmax);
  k_sexp<<<RB, 256, 0, stream>>>(logits, gmax, sel, gsum);
  k_snorm<<<gN, 256, 0, stream>>>(sel, gsum);
}

// Round 12
// 298.570 us; speedup vs baseline: 1.3621x; 1.0721x over previous
//
#include <hip/hip_runtime.h>
#include <hip/hip_fp16.h>
#include <math.h>

#define NN 100000
#define NE 1000000
#define CAP 32        // bucket capacity per node; degrees ~Poisson(10), max ~27
#define OVCAP 4096    // overflow list capacity (correct fallback, ~never used)
#define NDEG 391      // ceil(NN/256) degsum blocks
#define NGEMM 1024
#define NEB 3907      // ceil(NE/256) bucket blocks
// H = 64 channels. Feature matrices xw/h stored fp16 (arithmetic stays f32):
// per-edge row fetch 256B->128B. Error budget: fp16 rel ~5e-4 -> rr abs err
// ~2.5e-6 vs 1.5e-4 threshold (60x margin).

// ---------------- bucket build (measured floor ~73us; R10 falsified
// placement-based fixes: writeback = 1 line/edge, temporal) ----------------

__global__ __launch_bounds__(256) void k_bucket(const int* __restrict__ src,
                                                const int* __restrict__ dst,
                                                const float* __restrict__ ew,
                                                int* __restrict__ cnt,
                                                int2* __restrict__ bucket,
                                                int4* __restrict__ ovf,
                                                int* __restrict__ ovf_n) {
  int e = blockIdx.x * 256 + threadIdx.x;
  if (e < NE) {
    int s = src[e];
    int d = dst[e];
    float w = ew[e];
    int pos = atomicAdd(&cnt[d], 1);
    if (pos < CAP) {
      bucket[d * CAP + pos] = make_int2(s, __float_as_int(w));
    } else {
      int t = atomicAdd(ovf_n, 1);
      if (t < OVCAP) ovf[t] = make_int4(s, d, __float_as_int(w), 0);
    }
  }
}

// ---------------- fused: degsum (needs bucket) + GEMM1 (independent) ----------------
// GEMM1: X f32 input -> Y fp16.

__global__ __launch_bounds__(256) void k_degsum_gemm(const int* __restrict__ cnt,
                                                     const int2* __restrict__ bucket,
                                                     const int4* __restrict__ ovf,
                                                     const int* __restrict__ ovf_n,
                                                     float* __restrict__ dinv,
                                                     const float* __restrict__ X,
                                                     const float* __restrict__ W,
                                                     __half* __restrict__ Y) {
  int bid = blockIdx.x;
  if (bid < NDEG) {
    int i = bid * 256 + threadIdx.x;
    if (i >= NN) return;
    int c = cnt[i];
    int cc = c < CAP ? c : CAP;
    float dsum = 1.0f;  // self-loop weight
    const int2* bk = bucket + (size_t)i * CAP;
    for (int j = 0; j < cc; ++j) dsum += __int_as_float(bk[j].y);
    if (c > CAP) {
      int on = ovf_n[0]; if (on > OVCAP) on = OVCAP;
      for (int t = 0; t < on; ++t) {
        int4 o = ovf[t];
        if (o.y == i) dsum += __int_as_float(o.z);
      }
    }
    dinv[i] = 1.0f / sqrtf(dsum);
  } else {
    int lane = threadIdx.x & 63;
    int wid = (bid - NDEG) * 4 + (threadIdx.x >> 6);
    int nw = NGEMM * 4;
    float wcol[64];
#pragma unroll
    for (int k = 0; k < 64; ++k) wcol[k] = W[k * 64 + lane];
    for (int node = wid; node < NN; node += nw) {
      float xv = X[node * 64 + lane];
      float acc = 0.0f;
#pragma unroll
      for (int k = 0; k < 64; ++k) {
        float xb = __int_as_float(__builtin_amdgcn_readlane(__float_as_int(xv), k));
        acc = fmaf(xb, wcol[k], acc);
      }
      Y[node * 64 + lane] = __float2half(acc);
    }
  }
}

// ---------------- GEMM2: X fp16 input -> Y fp16 ----------------

__global__ __launch_bounds__(256) void k_gemm64h(const __half* __restrict__ X,
                                                 const float* __restrict__ W,
                                                 __half* __restrict__ Y) {
  int lane = threadIdx.x & 63;
  int wid = blockIdx.x * 4 + (threadIdx.x >> 6);
  int nw = gridDim.x * 4;
  float wcol[64];
#pragma unroll
  for (int k = 0; k < 64; ++k) wcol[k] = W[k * 64 + lane];
  for (int node = wid; node < NN; node += nw) {
    float xv = __half2float(X[node * 64 + lane]);
    float acc = 0.0f;
#pragma unroll
    for (int k = 0; k < 64; ++k) {
      float xb = __int_as_float(__builtin_amdgcn_readlane(__float_as_int(xv), k));
      acc = fmaf(xb, wcol[k], acc);
    }
    Y[node * 64 + lane] = __float2half(acc);
  }
}

// ---------------- gather core: 4 nodes/wave, 16 lanes/node, fp16 rows ----------------
// Lane l = tid&15 owns channels [4l,4l+4): one 8B load per edge-row.

__device__ __forceinline__ float4 h4load(const __half* p) {
  float2 raw = *(const float2*)p;  // 4 halfs in one dwordx2
  __half2 a = *(__half2*)&raw.x;
  __half2 b = *(__half2*)&raw.y;
  float2 fa = __half22float2(a), fb = __half22float2(b);
  return make_float4(fa.x, fa.y, fb.x, fb.y);
}

__device__ __forceinline__ float4 gather_node(const __half* __restrict__ xw,
                                              const float* __restrict__ dinv,
                                              const int* __restrict__ cnt,
                                              const int2* __restrict__ bucket,
                                              const int4* __restrict__ ovf,
                                              const int* __restrict__ ovf_n,
                                              int node, int l, float di) {
  int c = cnt[node];
  int cc = c < CAP ? c : CAP;
  const int4* bk4 = (const int4*)(bucket + (size_t)node * CAP);
  float4 acc = make_float4(0.f, 0.f, 0.f, 0.f);

  int j = 0;
  for (; j + 4 <= cc; j += 4) {
    int4 pa = bk4[j >> 1];
    int4 pb = bk4[(j >> 1) + 1];
    const float4 x0 = h4load(xw + (size_t)pa.x * 64 + l * 4);
    const float4 x1 = h4load(xw + (size_t)pa.z * 64 + l * 4);
    const float4 x2 = h4load(xw + (size_t)pb.x * 64 + l * 4);
    const float4 x3 = h4load(xw + (size_t)pb.z * 64 + l * 4);
    float v0 = dinv[pa.x] * __int_as_float(pa.y) * di;
    float v1 = dinv[pa.z] * __int_as_float(pa.w) * di;
    float v2 = dinv[pb.x] * __int_as_float(pb.y) * di;
    float v3 = dinv[pb.z] * __int_as_float(pb.w) * di;
    acc.x = fmaf(x0.x, v0, acc.x); acc.y = fmaf(x0.y, v0, acc.y);
    acc.z = fmaf(x0.z, v0, acc.z); acc.w = fmaf(x0.w, v0, acc.w);
    acc.x = fmaf(x1.x, v1, acc.x); acc.y = fmaf(x1.y, v1, acc.y);
    acc.z = fmaf(x1.z, v1, acc.z); acc.w = fmaf(x1.w, v1, acc.w);
    acc.x = fmaf(x2.x, v2, acc.x); acc.y = fmaf(x2.y, v2, acc.y);
    acc.z = fmaf(x2.z, v2, acc.z); acc.w = fmaf(x2.w, v2, acc.w);
    acc.x = fmaf(x3.x, v3, acc.x); acc.y = fmaf(x3.y, v3, acc.y);
    acc.z = fmaf(x3.z, v3, acc.z); acc.w = fmaf(x3.w, v3, acc.w);
  }
  const int2* bk = (const int2*)bk4;
  for (; j < cc; ++j) {
    int2 E = bk[j];
    const float4 xa = h4load(xw + (size_t)E.x * 64 + l * 4);
    float v = dinv[E.x] * __int_as_float(E.y) * di;
    acc.x = fmaf(xa.x, v, acc.x); acc.y = fmaf(xa.y, v, acc.y);
    acc.z = fmaf(xa.z, v, acc.z); acc.w = fmaf(xa.w, v, acc.w);
  }
  if (c > CAP) {
    int on = ovf_n[0]; if (on > OVCAP) on = OVCAP;
    for (int t = 0; t < on; ++t) {
      int4 o = ovf[t];
      if (o.y == node) {
        const float4 xa = h4load(xw + (size_t)o.x * 64 + l * 4);
        float v = dinv[o.x] * __int_as_float(o.z) * di;
        acc.x = fmaf(xa.x, v, acc.x); acc.y = fmaf(xa.y, v, acc.y);
        acc.z = fmaf(xa.z, v, acc.z); acc.w = fmaf(xa.w, v, acc.w);
      }
    }
  }
  // self-loop
  const float4 xs = h4load(xw + (size_t)node * 64 + l * 4);
  float dd = di * di;
  acc.x = fmaf(xs.x, dd, acc.x); acc.y = fmaf(xs.y, dd, acc.y);
  acc.z = fmaf(xs.z, dd, acc.z); acc.w = fmaf(xs.w, dd, acc.w);
  return acc;
}

// ---------------- layer-1 aggregation: gather + bias + ReLU -> h (fp16) ----------------

__global__ __launch_bounds__(256) void k_gather_l1(const __half* __restrict__ xw,
                                                   const float* __restrict__ dinv,
                                                   const int* __restrict__ cnt,
                                                   const int2* __restrict__ bucket,
                                                   const int4* __restrict__ ovf,
                                                   const int* __restrict__ ovf_n,
                                                   const float* __restrict__ b,
                                                   __half* __restrict__ h) {
  int l = threadIdx.x & 15;
  int node = blockIdx.x * 16 + (threadIdx.x >> 4);
  float di = dinv[node];
  float4 acc = gather_node(xw, dinv, cnt, bucket, ovf, ovf_n, node, l, di);
  const float4 b4 = *(const float4*)(b + l * 4);
  float2 st;
  __half2 h01 = __float22half2_rn(make_float2(fmaxf(acc.x + b4.x, 0.f),
                                              fmaxf(acc.y + b4.y, 0.f)));
  __half2 h23 = __float22half2_rn(make_float2(fmaxf(acc.z + b4.z, 0.f),
                                              fmaxf(acc.w + b4.w, 0.f)));
  st.x = *(float*)&h01;
  st.y = *(float*)&h23;
  *(float2*)(h + (size_t)node * 64 + l * 4) = st;  // 8B/lane, full-wave 512B store
}

// ---------------- layer-2 aggregation fused with both heads ----------------

__global__ __launch_bounds__(256) void k_gather_l2_heads(const __half* __restrict__ xw,
                                                         const float* __restrict__ dinv,
                                                         const int* __restrict__ cnt,
                                                         const int2* __restrict__ bucket,
                                                         const int4* __restrict__ ovf,
                                                         const int* __restrict__ ovf_n,
                                                         const float* __restrict__ b2,
                                                         const float* __restrict__ Wn,
                                                         const float* __restrict__ bn,
                                                         const float* __restrict__ Wr,
                                                         const float* __restrict__ br,
                                                         float* __restrict__ logits,
                                                         float* __restrict__ rr) {
  int l = threadIdx.x & 15;
  int node = blockIdx.x * 16 + (threadIdx.x >> 4);
  float di = dinv[node];
  float4 acc = gather_node(xw, dinv, cnt, bucket, ovf, ovf_n, node, l, di);
  const float4 b4 = *(const float4*)(b2 + l * 4);
  float4 r;
  r.x = fmaxf(acc.x + b4.x, 0.f); r.y = fmaxf(acc.y + b4.y, 0.f);
  r.z = fmaxf(acc.z + b4.z, 0.f); r.w = fmaxf(acc.w + b4.w, 0.f);
  const float4 wn4 = *(const float4*)(Wn + l * 4);
  const float4 wr4 = *(const float4*)(Wr + l * 4);
  float an = r.x * wn4.x + r.y * wn4.y + r.z * wn4.z + r.w * wn4.w;
  float ar = r.x * wr4.x + r.y * wr4.y + r.z * wr4.z + r.w * wr4.w;
#pragma unroll
  for (int m = 8; m > 0; m >>= 1) {
    an += __shfl_xor(an, m, 64);
    ar += __shfl_xor(ar, m, 64);
  }
  if (l == 0) {
    logits[node] = an + bn[0];
    float xr = ar + br[0];
    rr[node] = 0.01f / (1.0f + expf(-xr));
  }
}

// ---------------- softmax ----------------

#define RB 256  // reduction grid

__global__ __launch_bounds__(256) void k_smax_partial(const float* __restrict__ logits,
                                                      float* __restrict__ part) {
  __shared__ float s[256];
  float m = -INFINITY;
  for (int i = blockIdx.x * 256 + threadIdx.x; i < NN; i += RB * 256)
    m = fmaxf(m, logits[i]);
  s[threadIdx.x] = m;
  __syncthreads();
  for (int w = 128; w > 0; w >>= 1) {
    if (threadIdx.x < w) s[threadIdx.x] = fmaxf(s[threadIdx.x], s[threadIdx.x + w]);
    __syncthreads();
  }
  if (threadIdx.x == 0) part[blockIdx.x] = s[0];
}

__global__ __launch_bounds__(256) void k_smax_final(const float* __restrict__ part,
                                                    float* __restrict__ gmax) {
  __shared__ float s[256];
  s[threadIdx.x] = part[threadIdx.x];
  __syncthreads();
  for (int w = 128; w > 0; w >>= 1) {
    if (threadIdx.x < w) s[threadIdx.x] = fmaxf(s[threadIdx.x], s[threadIdx.x + w]);
    __syncthreads();
  }
  if (threadIdx.x == 0) gmax[0] = s[0];
}

// exp + block sums + 256-atomic global sum (256 funnel atomics ~ 4us, OK)
__global__ __launch_bounds__(256) void k_sexp(const float* __restrict__ logits,
                                              const float* __restrict__ gmax,
                                              float* __restrict__ sel,
                                              float* __restrict__ gsum) {
  __shared__ float s[256];
  float m = gmax[0];
  float acc = 0.0f;
  for (int i = blockIdx.x * 256 + threadIdx.x; i < NN; i += RB * 256) {
    float e = expf(logits[i] - m);
    sel[i] = e;
    acc += e;
  }
  s[threadIdx.x] = acc;
  __syncthreads();
  for (int w = 128; w > 0; w >>= 1) {
    if (threadIdx.x < w) s[threadIdx.x] += s[threadIdx.x + w];
    __syncthreads();
  }
  if (threadIdx.x == 0) unsafeAtomicAdd(gsum, s[0]);
}

__global__ __launch_bounds__(256) void k_snorm(float* __restrict__ sel,
                                               const float* __restrict__ gsum) {
  int i = blockIdx.x * 256 + threadIdx.x;
  if (i < NN) sel[i] *= (1.0f / gsum[0]);
}

// ---------------- launch ----------------

extern "C" void kernel_launch(void* const* d_in, const int* in_sizes, int n_in,
                              void* d_out, int out_size, void* d_ws, size_t ws_size,
                              hipStream_t stream) {
  const float* x  = (const float*)d_in[0];
  const int*   ei = (const int*)d_in[1];   // [2, E]: src row then dst row
  const float* ew = (const float*)d_in[2];
  const float* W1 = (const float*)d_in[3];
  const float* b1 = (const float*)d_in[4];
  const float* W2 = (const float*)d_in[5];
  const float* b2 = (const float*)d_in[6];
  const float* Wn = (const float*)d_in[7];
  const float* bn = (const float*)d_in[8];
  const float* Wr = (const float*)d_in[9];
  const float* br = (const float*)d_in[10];
  const int* src = ei;
  const int* dst = ei + NE;

  // ws layout (byte offsets, all regions 16B-aligned)
  char* wsb = (char*)d_ws;
  __half* xw     = (__half*)wsb;                        // 12,800,000 B
  __half* h      = (__half*)(wsb + 12800000);           // 12,800,000 B
  float*  dinv   = (float*)(wsb + 25600000);            // 400,000 B
  float*  logits = (float*)(wsb + 26000000);            // 400,000 B
  int2*   bucket = (int2*)(wsb + 26400000);             // 25,600,000 B
  int4*   ovf    = (int4*)(wsb + 52000000);             // 65,536 B
  int*    cnt    = (int*)(wsb + 52065536);              // 400,000 B  -- memset from here
  int*    ovf_n  = cnt + NN;                            // 4 B
  float*  gsum   = (float*)(ovf_n + 1);                 // 4 B        -- memset to here
  float*  part1  = gsum + 1;                            // 1024 B
  float*  gmax   = part1 + 256;                         // 4 B

  float* sel = (float*)d_out;                           // node_selector [N]
  float* rr  = (float*)d_out + NN;                      // rescue_ratios [N]

  int gN   = (NN + 255) / 256;
  int gN16 = NN / 16;  // 6250, exact

  // zero cnt + ovf_n + gsum in one memset
  hipMemsetAsync(cnt, 0, (size_t)(NN + 2) * 4, stream);

  // ---- bucket build ----
  k_bucket<<<NEB, 256, 0, stream>>>(src, dst, ew, cnt, bucket, ovf, ovf_n);

  // ---- degsum (bucket-dependent) co-scheduled with GEMM1 (independent) ----
  k_degsum_gemm<<<NDEG + NGEMM, 256, 0, stream>>>(cnt, bucket, ovf, ovf_n, dinv,
                                                  x, W1, xw);

  // ---- layer 1 aggregation ----
  k_gather_l1<<<gN16, 256, 0, stream>>>(xw, dinv, cnt, bucket, ovf, ovf_n, b1, h);

  // ---- layer 2: gemm (fp16 in/out) -> gather fused with heads ----
  k_gemm64h<<<1024, 256, 0, stream>>>(h, W2, xw);
  k_gather_l2_heads<<<gN16, 256, 0, stream>>>(xw, dinv, cnt, bucket, ovf, ovf_n,
                                              b2, Wn, bn, Wr, br, logits, rr);

  // ---- softmax ----
  k_smax_partial<<<RB, 256, 0, stream>>>(logits, part1);
  k_smax_final<<<1, 256, 0, stream>>>(part1, gmax);
  k_sexp<<<RB, 256, 0, stream>>>(logits, gmax, sel, gsum);
  k_snorm<<<gN, 256, 0, stream>>>(sel, gsum);
}

// Round 13
// 255.748 us; speedup vs baseline: 1.5901x; 1.1674x over previous
//
#include <hip/hip_runtime.h>
#include <hip/hip_fp16.h>
#include <math.h>

#define NN 100000
#define NE 1000000
#define CAP 32        // bucket capacity per node; degrees ~Poisson(10), max ~27
#define OVCAP 4096    // overflow list capacity (correct fallback, ~never used)
#define NEB 3907      // ceil(NE/256) bucket blocks
#define NTILE 6250    // NN/16 MFMA row-tiles
#define RB 256        // softmax reduction grid
// H = 64. Features stored fp16 with dinv[src] PRE-FOLDED: xw'[i] = dinv[i]*(X@W)[i].
// Gather: acc = sum_e ew*xw'[src] + xw'[self]; out = acc*dinv[dst].

typedef _Float16 half8 __attribute__((ext_vector_type(8)));
typedef float f32x4 __attribute__((ext_vector_type(4)));

// ---------------- bucket build (measured floor ~75us; R10 falsified
// placement fixes: writeback = 1 line/edge, temporal) ----------------

__global__ __launch_bounds__(256) void k_bucket(const int* __restrict__ src,
                                                const int* __restrict__ dst,
                                                const float* __restrict__ ew,
                                                int* __restrict__ cnt,
                                                int2* __restrict__ bucket,
                                                int4* __restrict__ ovf,
                                                int* __restrict__ ovf_n) {
  int e = blockIdx.x * 256 + threadIdx.x;
  if (e < NE) {
    int s = src[e];
    int d = dst[e];
    float w = ew[e];
    int pos = atomicAdd(&cnt[d], 1);
    if (pos < CAP) {
      bucket[d * CAP + pos] = make_int2(s, __float_as_int(w));
    } else {
      int t = atomicAdd(ovf_n, 1);
      if (t < OVCAP) ovf[t] = make_int4(s, d, __float_as_int(w), 0);
    }
  }
}

// ---------------- weighted degree -> dinv (no atomics) ----------------

__global__ __launch_bounds__(256) void k_degsum(const int* __restrict__ cnt,
                                                const int2* __restrict__ bucket,
                                                const int4* __restrict__ ovf,
                                                const int* __restrict__ ovf_n,
                                                float* __restrict__ dinv) {
  int i = blockIdx.x * 256 + threadIdx.x;
  if (i >= NN) return;
  int c = cnt[i];
  int cc = c < CAP ? c : CAP;
  float dsum = 1.0f;  // self-loop weight
  const int2* bk = bucket + (size_t)i * CAP;
  for (int j = 0; j < cc; ++j) dsum += __int_as_float(bk[j].y);
  if (c > CAP) {
    int on = ovf_n[0]; if (on > OVCAP) on = OVCAP;
    for (int t = 0; t < on; ++t) {
      int4 o = ovf[t];
      if (o.y == i) dsum += __int_as_float(o.z);
    }
  }
  dinv[i] = 1.0f / sqrtf(dsum);
}

// ---------------- MFMA GEMM: Y'[i] = dinv[i] * (X @ W)[i], fp16 out ----------------
// 16x16x32_f16. A: m=lane&15, k=(lane>>4)*8+j (16B row chunks). B staged via
// LDS in fragment layout (k=(lane>>4)*8+j, n=lane&15), loaded once per block.
// C/D: col=lane&15, row=(lane>>4)*4+reg [m89-verified].

__device__ __forceinline__ void stage_B_lds(const float* __restrict__ W,
                                            _Float16* __restrict__ ldsB) {
  for (int u = threadIdx.x; u < 512; u += 256) {
    int slane = u & 63, ts = u >> 6;
    int t = ts >> 1, s = ts & 1;
    int qq = slane >> 4, ll = slane & 15;
#pragma unroll
    for (int j = 0; j < 8; ++j)
      ldsB[u * 8 + j] = (_Float16)W[(s * 32 + qq * 8 + j) * 64 + t * 16 + ll];
  }
}

__global__ __launch_bounds__(256) void k_gemm_mfma_f32(const float* __restrict__ X,
                                                       const float* __restrict__ W,
                                                       const float* __restrict__ dinv,
                                                       __half* __restrict__ Y) {
  __shared__ _Float16 ldsB[4096];
  stage_B_lds(W, ldsB);
  __syncthreads();
  int lane = threadIdx.x & 63;
  int l15 = lane & 15, q = lane >> 4;
  half8 bfr[4][2];
#pragma unroll
  for (int t = 0; t < 4; ++t)
#pragma unroll
    for (int s = 0; s < 2; ++s)
      bfr[t][s] = *(half8*)&ldsB[((t * 2 + s) * 64 + lane) * 8];

  int wid = blockIdx.x * 4 + (threadIdx.x >> 6);
  for (int tile = wid; tile < NTILE; tile += 2048) {
    int row = tile * 16 + l15;
    f32x4 acc[4] = {{0.f,0.f,0.f,0.f},{0.f,0.f,0.f,0.f},
                    {0.f,0.f,0.f,0.f},{0.f,0.f,0.f,0.f}};
#pragma unroll
    for (int s = 0; s < 2; ++s) {
      const float* ap = X + (size_t)row * 64 + s * 32 + q * 8;
      float4 a0 = *(const float4*)ap;
      float4 a1 = *(const float4*)(ap + 4);
      half8 af;
      af[0] = (_Float16)a0.x; af[1] = (_Float16)a0.y;
      af[2] = (_Float16)a0.z; af[3] = (_Float16)a0.w;
      af[4] = (_Float16)a1.x; af[5] = (_Float16)a1.y;
      af[6] = (_Float16)a1.z; af[7] = (_Float16)a1.w;
#pragma unroll
      for (int t = 0; t < 4; ++t)
        acc[t] = __builtin_amdgcn_mfma_f32_16x16x32_f16(af, bfr[t][s], acc[t], 0, 0, 0);
    }
#pragma unroll
    for (int r = 0; r < 4; ++r) {
      int rw = tile * 16 + q * 4 + r;
      float dv = dinv[rw];
#pragma unroll
      for (int t = 0; t < 4; ++t)
        Y[(size_t)rw * 64 + t * 16 + l15] = __float2half(acc[t][r] * dv);
    }
  }
}

__global__ __launch_bounds__(256) void k_gemm_mfma_f16(const __half* __restrict__ X,
                                                       const float* __restrict__ W,
                                                       const float* __restrict__ dinv,
                                                       __half* __restrict__ Y) {
  __shared__ _Float16 ldsB[4096];
  stage_B_lds(W, ldsB);
  __syncthreads();
  int lane = threadIdx.x & 63;
  int l15 = lane & 15, q = lane >> 4;
  half8 bfr[4][2];
#pragma unroll
  for (int t = 0; t < 4; ++t)
#pragma unroll
    for (int s = 0; s < 2; ++s)
      bfr[t][s] = *(half8*)&ldsB[((t * 2 + s) * 64 + lane) * 8];

  int wid = blockIdx.x * 4 + (threadIdx.x >> 6);
  for (int tile = wid; tile < NTILE; tile += 2048) {
    int row = tile * 16 + l15;
    f32x4 acc[4] = {{0.f,0.f,0.f,0.f},{0.f,0.f,0.f,0.f},
                    {0.f,0.f,0.f,0.f},{0.f,0.f,0.f,0.f}};
#pragma unroll
    for (int s = 0; s < 2; ++s) {
      half8 af = *(const half8*)((const _Float16*)X + (size_t)row * 64 + s * 32 + q * 8);
#pragma unroll
      for (int t = 0; t < 4; ++t)
        acc[t] = __builtin_amdgcn_mfma_f32_16x16x32_f16(af, bfr[t][s], acc[t], 0, 0, 0);
    }
#pragma unroll
    for (int r = 0; r < 4; ++r) {
      int rw = tile * 16 + q * 4 + r;
      float dv = dinv[rw];
#pragma unroll
      for (int t = 0; t < 4; ++t)
        Y[(size_t)rw * 64 + t * 16 + l15] = __float2half(acc[t][r] * dv);
    }
  }
}

// ---------------- gather core: 4 nodes/wave, 16 lanes/node, fp16 rows ----------------
// dinv pre-folded into xw': per-edge work is just fmaf(xw'[src], ew, acc).

__device__ __forceinline__ float4 h4load(const __half* p) {
  float2 raw = *(const float2*)p;  // 4 halfs in one dwordx2
  __half2 a = *(__half2*)&raw.x;
  __half2 b = *(__half2*)&raw.y;
  float2 fa = __half22float2(a), fb = __half22float2(b);
  return make_float4(fa.x, fa.y, fb.x, fb.y);
}

__device__ __forceinline__ float4 gather_node(const __half* __restrict__ xw,
                                              const int* __restrict__ cnt,
                                              const int2* __restrict__ bucket,
                                              const int4* __restrict__ ovf,
                                              const int* __restrict__ ovf_n,
                                              int node, int l) {
  int c = cnt[node];
  int cc = c < CAP ? c : CAP;
  const int4* bk4 = (const int4*)(bucket + (size_t)node * CAP);
  float4 acc = make_float4(0.f, 0.f, 0.f, 0.f);

  int j = 0;
  for (; j + 4 <= cc; j += 4) {
    int4 pa = bk4[j >> 1];
    int4 pb = bk4[(j >> 1) + 1];
    const float4 x0 = h4load(xw + (size_t)pa.x * 64 + l * 4);
    const float4 x1 = h4load(xw + (size_t)pa.z * 64 + l * 4);
    const float4 x2 = h4load(xw + (size_t)pb.x * 64 + l * 4);
    const float4 x3 = h4load(xw + (size_t)pb.z * 64 + l * 4);
    float v0 = __int_as_float(pa.y);
    float v1 = __int_as_float(pa.w);
    float v2 = __int_as_float(pb.y);
    float v3 = __int_as_float(pb.w);
    acc.x = fmaf(x0.x, v0, acc.x); acc.y = fmaf(x0.y, v0, acc.y);
    acc.z = fmaf(x0.z, v0, acc.z); acc.w = fmaf(x0.w, v0, acc.w);
    acc.x = fmaf(x1.x, v1, acc.x); acc.y = fmaf(x1.y, v1, acc.y);
    acc.z = fmaf(x1.z, v1, acc.z); acc.w = fmaf(x1.w, v1, acc.w);
    acc.x = fmaf(x2.x, v2, acc.x); acc.y = fmaf(x2.y, v2, acc.y);
    acc.z = fmaf(x2.z, v2, acc.z); acc.w = fmaf(x2.w, v2, acc.w);
    acc.x = fmaf(x3.x, v3, acc.x); acc.y = fmaf(x3.y, v3, acc.y);
    acc.z = fmaf(x3.z, v3, acc.z); acc.w = fmaf(x3.w, v3, acc.w);
  }
  const int2* bk = (const int2*)bk4;
  for (; j < cc; ++j) {
    int2 E = bk[j];
    const float4 xa = h4load(xw + (size_t)E.x * 64 + l * 4);
    float v = __int_as_float(E.y);
    acc.x = fmaf(xa.x, v, acc.x); acc.y = fmaf(xa.y, v, acc.y);
    acc.z = fmaf(xa.z, v, acc.z); acc.w = fmaf(xa.w, v, acc.w);
  }
  if (c > CAP) {
    int on = ovf_n[0]; if (on > OVCAP) on = OVCAP;
    for (int t = 0; t < on; ++t) {
      int4 o = ovf[t];
      if (o.y == node) {
        const float4 xa = h4load(xw + (size_t)o.x * 64 + l * 4);
        float v = __int_as_float(o.z);
        acc.x = fmaf(xa.x, v, acc.x); acc.y = fmaf(xa.y, v, acc.y);
        acc.z = fmaf(xa.z, v, acc.z); acc.w = fmaf(xa.w, v, acc.w);
      }
    }
  }
  // self-loop: xw'[self] with weight 1 (outer *dinv[dst] completes dinv^2)
  const float4 xs = h4load(xw + (size_t)node * 64 + l * 4);
  acc.x += xs.x; acc.y += xs.y; acc.z += xs.z; acc.w += xs.w;
  return acc;
}

// ---------------- layer-1 aggregation: gather*dinv + bias + ReLU -> h (fp16) ----------------

__global__ __launch_bounds__(256) void k_gather_l1(const __half* __restrict__ xw,
                                                   const float* __restrict__ dinv,
                                                   const int* __restrict__ cnt,
                                                   const int2* __restrict__ bucket,
                                                   const int4* __restrict__ ovf,
                                                   const int* __restrict__ ovf_n,
                                                   const float* __restrict__ b,
                                                   __half* __restrict__ h) {
  int l = threadIdx.x & 15;
  int node = blockIdx.x * 16 + (threadIdx.x >> 4);
  float4 acc = gather_node(xw, cnt, bucket, ovf, ovf_n, node, l);
  float di = dinv[node];
  const float4 b4 = *(const float4*)(b + l * 4);
  __half2 h01 = __float22half2_rn(make_float2(fmaxf(fmaf(acc.x, di, b4.x), 0.f),
                                              fmaxf(fmaf(acc.y, di, b4.y), 0.f)));
  __half2 h23 = __float22half2_rn(make_float2(fmaxf(fmaf(acc.z, di, b4.z), 0.f),
                                              fmaxf(fmaf(acc.w, di, b4.w), 0.f)));
  float2 st;
  st.x = *(float*)&h01;
  st.y = *(float*)&h23;
  *(float2*)(h + (size_t)node * 64 + l * 4) = st;
}

// ---------------- layer-2 aggregation + heads + per-block max partial ----------------

__global__ __launch_bounds__(256) void k_gather_l2_heads(const __half* __restrict__ xw,
                                                         const float* __restrict__ dinv,
                                                         const int* __restrict__ cnt,
                                                         const int2* __restrict__ bucket,
                                                         const int4* __restrict__ ovf,
                                                         const int* __restrict__ ovf_n,
                                                         const float* __restrict__ b2,
                                                         const float* __restrict__ Wn,
                                                         const float* __restrict__ bn,
                                                         const float* __restrict__ Wr,
                                                         const float* __restrict__ br,
                                                         float* __restrict__ logits,
                                                         float* __restrict__ rr,
                                                         float* __restrict__ part) {
  __shared__ float s[256];
  int l = threadIdx.x & 15;
  int node = blockIdx.x * 16 + (threadIdx.x >> 4);
  float4 acc = gather_node(xw, cnt, bucket, ovf, ovf_n, node, l);
  float di = dinv[node];
  const float4 b4 = *(const float4*)(b2 + l * 4);
  float4 r;
  r.x = fmaxf(fmaf(acc.x, di, b4.x), 0.f); r.y = fmaxf(fmaf(acc.y, di, b4.y), 0.f);
  r.z = fmaxf(fmaf(acc.z, di, b4.z), 0.f); r.w = fmaxf(fmaf(acc.w, di, b4.w), 0.f);
  const float4 wn4 = *(const float4*)(Wn + l * 4);
  const float4 wr4 = *(const float4*)(Wr + l * 4);
  float an = r.x * wn4.x + r.y * wn4.y + r.z * wn4.z + r.w * wn4.w;
  float ar = r.x * wr4.x + r.y * wr4.y + r.z * wr4.z + r.w * wr4.w;
#pragma unroll
  for (int m = 8; m > 0; m >>= 1) {
    an += __shfl_xor(an, m, 64);
    ar += __shfl_xor(ar, m, 64);
  }
  float lg = an + bn[0];
  if (l == 0) {
    logits[node] = lg;
    float xr = ar + br[0];
    rr[node] = 0.01f / (1.0f + expf(-xr));
  }
  // block max of 16 logits (every lane holds its group's lg; dups harmless)
  s[threadIdx.x] = lg;
  __syncthreads();
  for (int w = 128; w > 0; w >>= 1) {
    if (threadIdx.x < w) s[threadIdx.x] = fmaxf(s[threadIdx.x], s[threadIdx.x + w]);
    __syncthreads();
  }
  if (threadIdx.x == 0) part[blockIdx.x] = s[0];
}

// ---------------- softmax tail ----------------

__global__ __launch_bounds__(256) void k_smax_final(const float* __restrict__ part,
                                                    float* __restrict__ gmax) {
  __shared__ float s[256];
  float m = -INFINITY;
  for (int i = threadIdx.x; i < NTILE; i += 256) m = fmaxf(m, part[i]);
  s[threadIdx.x] = m;
  __syncthreads();
  for (int w = 128; w > 0; w >>= 1) {
    if (threadIdx.x < w) s[threadIdx.x] = fmaxf(s[threadIdx.x], s[threadIdx.x + w]);
    __syncthreads();
  }
  if (threadIdx.x == 0) gmax[0] = s[0];
}

// exp + block sums + 256-atomic global sum (256 funnel atomics ~ 4us, OK)
__global__ __launch_bounds__(256) void k_sexp(const float* __restrict__ logits,
                                              const float* __restrict__ gmax,
                                              float* __restrict__ sel,
                                              float* __restrict__ gsum) {
  __shared__ float s[256];
  float m = gmax[0];
  float acc = 0.0f;
  for (int i = blockIdx.x * 256 + threadIdx.x; i < NN; i += RB * 256) {
    float e = expf(logits[i] - m);
    sel[i] = e;
    acc += e;
  }
  s[threadIdx.x] = acc;
  __syncthreads();
  for (int w = 128; w > 0; w >>= 1) {
    if (threadIdx.x < w) s[threadIdx.x] += s[threadIdx.x + w];
    __syncthreads();
  }
  if (threadIdx.x == 0) unsafeAtomicAdd(gsum, s[0]);
}

__global__ __launch_bounds__(256) void k_snorm(float* __restrict__ sel,
                                               const float* __restrict__ gsum) {
  int i = blockIdx.x * 256 + threadIdx.x;
  if (i < NN) sel[i] *= (1.0f / gsum[0]);
}

// ---------------- launch ----------------

extern "C" void kernel_launch(void* const* d_in, const int* in_sizes, int n_in,
                              void* d_out, int out_size, void* d_ws, size_t ws_size,
                              hipStream_t stream) {
  const float* x  = (const float*)d_in[0];
  const int*   ei = (const int*)d_in[1];   // [2, E]: src row then dst row
  const float* ew = (const float*)d_in[2];
  const float* W1 = (const float*)d_in[3];
  const float* b1 = (const float*)d_in[4];
  const float* W2 = (const float*)d_in[5];
  const float* b2 = (const float*)d_in[6];
  const float* Wn = (const float*)d_in[7];
  const float* bn = (const float*)d_in[8];
  const float* Wr = (const float*)d_in[9];
  const float* br = (const float*)d_in[10];
  const int* src = ei;
  const int* dst = ei + NE;

  // ws layout (byte offsets, all regions 16B-aligned)
  char* wsb = (char*)d_ws;
  __half* xw     = (__half*)wsb;                        // 12,800,000 B
  __half* h      = (__half*)(wsb + 12800000);           // 12,800,000 B
  float*  dinv   = (float*)(wsb + 25600000);            // 400,000 B
  float*  logits = (float*)(wsb + 26000000);            // 400,000 B
  int2*   bucket = (int2*)(wsb + 26400000);             // 25,600,000 B
  int4*   ovf    = (int4*)(wsb + 52000000);             // 65,536 B
  int*    cnt    = (int*)(wsb + 52065536);              // 400,000 B  -- memset from here
  int*    ovf_n  = cnt + NN;                            // 4 B
  float*  gsum   = (float*)(ovf_n + 1);                 // 4 B        -- memset to here
  float*  gmax   = gsum + 1;                            // 4 B
  float*  part1  = gmax + 1;                            // 25,000 B (6250 floats)

  float* sel = (float*)d_out;                           // node_selector [N]
  float* rr  = (float*)d_out + NN;                      // rescue_ratios [N]

  int gN = (NN + 255) / 256;

  // zero cnt + ovf_n + gsum in one memset
  hipMemsetAsync(cnt, 0, (size_t)(NN + 2) * 4, stream);

  // ---- bucket build + dinv ----
  k_bucket<<<NEB, 256, 0, stream>>>(src, dst, ew, cnt, bucket, ovf, ovf_n);
  k_degsum<<<gN, 256, 0, stream>>>(cnt, bucket, ovf, ovf_n, dinv);

  // ---- layer 1: MFMA gemm (dinv-folded) -> gather ----
  k_gemm_mfma_f32<<<512, 256, 0, stream>>>(x, W1, dinv, xw);
  k_gather_l1<<<NTILE, 256, 0, stream>>>(xw, dinv, cnt, bucket, ovf, ovf_n, b1, h);

  // ---- layer 2: MFMA gemm (dinv-folded) -> gather + heads + max partial ----
  k_gemm_mfma_f16<<<512, 256, 0, stream>>>(h, W2, dinv, xw);
  k_gather_l2_heads<<<NTILE, 256, 0, stream>>>(xw, dinv, cnt, bucket, ovf, ovf_n,
                                               b2, Wn, bn, Wr, br, logits, rr, part1);

  // ---- softmax tail ----
  k_smax_final<<<1, 256, 0, stream>>>(part1, gmax);
  k_sexp<<<RB, 256, 0, stream>>>(logits, gmax, sel, gsum);
  k_snorm<<<gN, 256, 0, stream>>>(sel, gsum);
}